// Round 2
// baseline (81.384 us; speedup 1.0000x reference)
//
#include <hip/hip_runtime.h>

// CTC batch cost (Keras semantics, blank = C-1), full input/label lengths.
// B=1024, T=256, C=128, L=48, S=2L+1=97. One block per batch element.

#define TT 256
#define CC 128
#define LL 48
#define SS 97  // 2*LL+1

__device__ __forceinline__ float lse3f(float a, float b, float c) {
    float m = fmaxf(fmaxf(a, b), c);
    return m + __logf(__expf(a - m) + __expf(b - m) + __expf(c - m));
}

__global__ __launch_bounds__(128) void ctc_fwd_kernel(
    const float* __restrict__ y,       // [B, T, C] softmax probs
    const int* __restrict__ labels,    // [B, L]
    float* __restrict__ out)           // [B] (flat [B,1])
{
    const int b = blockIdx.x;
    const int tid = threadIdx.x;
    const float NEGF = -1e30f;
    const float EPS = 1e-7f;

    __shared__ float lp_sh[CC];        // log-probs of current time row, by class
    __shared__ float alpha_sh[SS + 2]; // [0,1] = NEG pad, [2..SS+1] = alpha[0..SS-1]
    __shared__ int ext_sh[SS];

    // Extended label: blank at even s, labels at odd s.
    if (tid < SS)
        ext_sh[tid] = (tid & 1) ? labels[b * LL + (tid >> 1)] : (CC - 1);
    if (tid < 2) alpha_sh[tid] = NEGF;
    __syncthreads();

    const int e = (tid < SS) ? ext_sh[tid] : (CC - 1);
    const bool cs = (tid >= 2) && (tid < SS) && (e != CC - 1) && (e != ext_sh[tid - 2]);

    const float* row = y + (size_t)b * TT * CC;
    float cur = row[tid];  // class `tid` of row t=0

    for (int t = 0; t < TT; ++t) {
        float nxt = 0.f;
        if (t + 1 < TT) nxt = row[(size_t)(t + 1) * CC + tid];  // prefetch

        lp_sh[tid] = __logf(cur + EPS);
        __syncthreads();

        float na = NEGF;
        if (tid < SS) {
            const float lpt = lp_sh[e];
            if (t == 0) {
                na = (tid < 2) ? lpt : NEGF;
            } else {
                const float a  = alpha_sh[tid + 2];
                const float a2 = alpha_sh[tid + 1];
                const float a3 = cs ? alpha_sh[tid] : NEGF;
                na = lse3f(a, a2, a3) + lpt;
            }
        }
        __syncthreads();
        if (tid < SS) alpha_sh[tid + 2] = na;
        cur = nxt;
    }
    __syncthreads();

    if (tid == 0) {
        const float x = alpha_sh[SS + 1];  // alpha[S-1] (last blank)
        const float z = alpha_sh[SS];      // alpha[S-2] (last label)
        const float m = fmaxf(x, z);
        out[b] = -(m + __logf(__expf(x - m) + __expf(z - m)));
    }
}

extern "C" void kernel_launch(void* const* d_in, const int* in_sizes, int n_in,
                              void* d_out, int out_size, void* d_ws, size_t ws_size,
                              hipStream_t stream) {
    const float* y = (const float*)d_in[0];
    const int* labels = (const int*)d_in[1];
    float* out = (float*)d_out;
    const int B = in_sizes[0] / (TT * CC);  // 1024
    ctc_fwd_kernel<<<B, 128, 0, stream>>>(y, labels, out);
}

// Round 3
// 65.816 us; speedup vs baseline: 1.2365x; 1.2365x over previous
//
#include <hip/hip_runtime.h>

// CTC batch cost (Keras semantics, blank = C-1). B=1024, T=256, C=128, L=48, S=97.
// One WAVE per batch element: lane l owns alpha[2l] (blank pos) and alpha[2l+1]
// (label pos). Even positions never allow the skip transition, so a full
// DP step needs only ONE shfl_up. No LDS, no barriers.

#define TT 256
#define CC 128
#define LL 48
#define PF 8   // prefetch depth (rows held in registers); divides TT

__global__ __launch_bounds__(256) void ctc_fwd_wave(
    const float* __restrict__ y,       // [B, T, C] softmax probs
    const int* __restrict__ labels,    // [B, L]
    float* __restrict__ out)           // [B]
{
    const int lane = threadIdx.x & 63;
    const int wave = threadIdx.x >> 6;
    const int b = blockIdx.x * 4 + wave;
    const float NEGF = -1e30f;
    const float EPS  = 1e-7f;

    // Per-lane label for odd position s = 2*lane+1 (lanes 0..47).
    int lab = CC - 1;                       // sentinel for unused lanes
    if (lane < LL) lab = labels[b * LL + lane];
    const int labprev = __shfl_up(lab, 1);
    const bool cs   = (lane > 0) && (lane < LL) && (lab != labprev); // skip allowed
    const bool use0 = (lab < 64);
    const int  labi = lab & 63;             // bpermute index (loop-invariant)

    const float* base = y + (size_t)b * TT * CC + lane;

    // Register prefetch ring: pr0/pr1 hold classes [lane] and [lane+64] of rows.
    float pr0[PF], pr1[PF];
#pragma unroll
    for (int i = 0; i < PF; ++i) {
        pr0[i] = base[(size_t)i * CC];
        pr1[i] = base[(size_t)i * CC + 64];
    }

    // Init so the uniform update at t=0 produces the reference alpha0:
    // lse2(a0,p)+lpb -> lpb at lane0 ; lse3(a1,a0old,·)+lpl -> lpl at lane0.
    float a0 = (lane == 0) ? 0.f : NEGF;
    float a1 = NEGF;

    for (int t = 0; t < TT; t += PF) {
#pragma unroll
        for (int j = 0; j < PF; ++j) {
            const float q0 = pr0[j], q1 = pr1[j];
            int rr = t + j + PF; rr = (rr < TT) ? rr : (TT - 1);   // clamp (safe re-read)
            pr0[j] = base[(size_t)rr * CC];
            pr1[j] = base[(size_t)rr * CC + 64];

            // Gather this row's blank prob and this lane's label prob.
            const float pb = __shfl(q1, 63);                 // class 127 (blank)
            const float g0 = __shfl(q0, labi);
            const float g1 = __shfl(q1, labi);
            const float pl = use0 ? g0 : g1;
            const float lpb = __logf(pb + EPS);
            const float lpl = __logf(pl + EPS);

            float p = __shfl_up(a1, 1);                      // alpha[2l-1] (old)
            if (lane == 0) p = NEGF;

            const float a0old = a0;
            // blank position s=2l: lse2(alpha[s], alpha[s-1]) + lp_blank
            {
                const float m = fmaxf(a0old, p);
                a0 = m + __logf(__expf(a0old - m) + __expf(p - m)) + lpb;
            }
            // label position s=2l+1: lse3(alpha[s], alpha[s-1], skip?alpha[s-2]) + lp_label
            {
                const float c = cs ? p : NEGF;
                const float m = fmaxf(fmaxf(a1, a0old), c);
                a1 = m + __logf(__expf(a1 - m) + __expf(a0old - m) + __expf(c - m)) + lpl;
            }
        }
    }

    // loss = -logaddexp(alpha[S-1], alpha[S-2]) = -lse2(alpha[96], alpha[95])
    const float v95 = __shfl(a1, 47);
    const float v96 = __shfl(a0, 48);
    if (lane == 0) {
        const float m = fmaxf(v95, v96);
        out[b] = -(m + __logf(__expf(v95 - m) + __expf(v96 - m)));
    }
}

extern "C" void kernel_launch(void* const* d_in, const int* in_sizes, int n_in,
                              void* d_out, int out_size, void* d_ws, size_t ws_size,
                              hipStream_t stream) {
    const float* y = (const float*)d_in[0];
    const int* labels = (const int*)d_in[1];
    float* out = (float*)d_out;
    const int B = in_sizes[0] / (TT * CC);   // 1024
    ctc_fwd_wave<<<B / 4, 256, 0, stream>>>(y, labels, out);
}